// Round 1
// baseline (12685.374 us; speedup 1.0000x reference)
//
#include <hip/hip_runtime.h>

// psRNN: state_{t+1} = A*cos(omega*state_t + Wi x_t + bi) + state_t @ Wh^T, 512 steps
// out = state_512 @ Wr^T + br
//
// Design: 4 replicas x 64 blocks (1 block/CU). Replica r owns batches [16r,16r+16).
// Block owns 32 output neurons (n0..n0+31). Wh slice (32x2048) lives in VGPRs as
// f16 MFMA B-fragments (loaded once). State is double-buffered in ws in MFMA
// A-fragment layout: half St[2][4][64 chunks][64 lanes][8], so each wave's state
// loads are contiguous dwordx4. Per-step sync: per-replica 64-entry monotonic
// flag array (agent-scope atomics). u_t and A*cos(...) are computed between
// barrier-arrive and barrier-wait to hide sync latency.

typedef _Float16 half_t;
typedef _Float16 half8 __attribute__((ext_vector_type(8)));
typedef float f32x4 __attribute__((ext_vector_type(4)));

#define T_STEPS 512
#define BATCH 64
#define NINP 64
#define NHID 2048
#define NOUT 64

#define MFMA16(A, B, C) __builtin_amdgcn_mfma_f32_16x16x32_f16(A, B, C, 0, 0, 0)

// ws layout:
//   [0, 1024)            : flags  uint[4][64]   (per-replica barrier flags)
//   [4096, 4096+512KB)   : St     half[2][4][64][64][8]  (parity, rep, chunk, lane, j)

__device__ __forceinline__ half8 cvt8(float4 lo, float4 hi) {
  half8 h;
  h[0] = (half_t)lo.x; h[1] = (half_t)lo.y; h[2] = (half_t)lo.z; h[3] = (half_t)lo.w;
  h[4] = (half_t)hi.x; h[5] = (half_t)hi.y; h[6] = (half_t)hi.z; h[7] = (half_t)hi.w;
  return h;
}

__global__ void psrnn_init_kernel(unsigned int* flags, half_t* st) {
  int tid = blockIdx.x * blockDim.x + threadIdx.x;  // 16384 threads
  const unsigned int one2 = 0x3C003C00u;            // two fp16 1.0
  uint4 v; v.x = one2; v.y = one2; v.z = one2; v.w = one2;
  ((uint4*)st)[tid] = v;                            // parity-0 state := 1.0 (256KB)
  if (tid < 256) flags[tid] = 0;
}

__global__ __launch_bounds__(256, 1) void psrnn_main_kernel(
    const float* __restrict__ x,      // [512][64][64]
    const float* __restrict__ Wi_w,   // [2048][64]
    const float* __restrict__ Wi_b,   // [2048]
    const float* __restrict__ Wh_w,   // [2048][2048]
    const float* __restrict__ Av,     // [2048]
    const float* __restrict__ Om,     // [2048]
    unsigned int* __restrict__ flags,
    half_t* __restrict__ St)
{
  const int tid   = threadIdx.x;
  const int wave  = tid >> 6;
  const int lane  = tid & 63;
  const int lm    = lane & 15;   // A-frag: batch row; B-frag: neuron col; C-frag: neuron col
  const int kg    = lane >> 4;   // k-group within frag
  const int bx    = blockIdx.x;
  const int xcd   = bx & 7;
  const int rep   = xcd >> 1;                      // replica = XCD pair
  const int local = ((bx >> 3) << 1) | (xcd & 1);  // 0..63 within replica
  const int n0    = local * 32;                    // this block's neuron range
  const int b0    = rep * 16;                      // this replica's batch range

  __shared__ float red_y[4][2][16][17];  // [wave][tile][batch][neuron] K-partials
  __shared__ float red_u[2][16][17];     // u partials (wave0 writes)
  __shared__ float cA[32], cOm[32], cWib[32];

  if (tid < 32) {
    cA[tid]   = Av[n0 + tid];
    cOm[tid]  = Om[n0 + tid];
    cWib[tid] = Wi_b[n0 + tid];
  }

  // --- Wh slice -> VGPR B-fragments. breg[nt][c]: neurons n0+nt*16+lm, K chunk wave*16+c
  half8 breg[2][16];
#pragma unroll
  for (int nt = 0; nt < 2; ++nt) {
#pragma unroll
    for (int c = 0; c < 16; ++c) {
      const float* p = Wh_w + (size_t)(n0 + nt * 16 + lm) * NHID + (wave * 512 + c * 32 + kg * 8);
      breg[nt][c] = cvt8(*(const float4*)p, *(const float4*)(p + 4));
    }
  }
  // --- Wi slice B-fragments (K=64 -> 2 chunks), used by wave 0
  half8 wiReg[2][2];
#pragma unroll
  for (int nt = 0; nt < 2; ++nt) {
#pragma unroll
    for (int c2 = 0; c2 < 2; ++c2) {
      const float* p = Wi_w + (size_t)(n0 + nt * 16 + lm) * NINP + (c2 * 32 + kg * 8);
      wiReg[nt][c2] = cvt8(*(const float4*)p, *(const float4*)(p + 4));
    }
  }

  unsigned int* f = flags + rep * 64;

  // epilogue mapping: this thread owns outputs (batch em, neurons n0+en and n0+16+en)
  const int em = tid >> 4;
  const int en = tid & 15;
  const int st_o0 = (local * 64 + ((en >> 3)) * 16 + em) * 8 + (en & 7);       // tile0 frag addr
  const int st_o1 = (local * 64 + (2 + (en >> 3)) * 16 + em) * 8 + (en & 7);   // tile1 frag addr

  float s0 = 1.0f, s1 = 1.0f;  // fp32 master state for the cos path

  // preload x fragments for t=0
  float4 xr0, xr1, xr2, xr3;
  {
    const float* xp = x + (size_t)(b0 + lm) * NINP;
    xr0 = *(const float4*)(xp + kg * 8);
    xr1 = *(const float4*)(xp + kg * 8 + 4);
    xr2 = *(const float4*)(xp + 32 + kg * 8);
    xr3 = *(const float4*)(xp + 32 + kg * 8 + 4);
  }

  for (int t = 0; t < T_STEPS; ++t) {
    const int cur = t & 1;
    const half_t* stc = St + (size_t)(cur * 4 + rep) * 32768;
    half_t* stn = St + (size_t)((cur ^ 1) * 4 + rep) * 32768;

    // ---- local phase (overlaps others finishing step t-1): u_t = x_t @ Wi^T
    if (wave == 0) {
      half8 xa0 = cvt8(xr0, xr1);
      half8 xa1 = cvt8(xr2, xr3);
      f32x4 au0 = {0.f, 0.f, 0.f, 0.f}, au1 = {0.f, 0.f, 0.f, 0.f};
      au0 = MFMA16(xa0, wiReg[0][0], au0);
      au1 = MFMA16(xa0, wiReg[1][0], au1);
      au0 = MFMA16(xa1, wiReg[0][1], au0);
      au1 = MFMA16(xa1, wiReg[1][1], au1);
#pragma unroll
      for (int r = 0; r < 4; ++r) {
        red_u[0][kg * 4 + r][lm] = au0[r];
        red_u[1][kg * 4 + r][lm] = au1[r];
      }
      if (t + 1 < T_STEPS) {  // prefetch x for t+1
        const float* xp = x + ((size_t)(t + 1) * BATCH + b0 + lm) * NINP;
        xr0 = *(const float4*)(xp + kg * 8);
        xr1 = *(const float4*)(xp + kg * 8 + 4);
        xr2 = *(const float4*)(xp + 32 + kg * 8);
        xr3 = *(const float4*)(xp + 32 + kg * 8 + 4);
      }
    }
    __syncthreads();

    const float u0 = red_u[0][em][en] + cWib[en];
    const float u1 = red_u[1][em][en] + cWib[16 + en];
    const float ca0 = cA[en]      * cosf(cOm[en]      * s0 + u0);
    const float ca1 = cA[16 + en] * cosf(cOm[16 + en] * s1 + u1);

    // ---- wait: all replica members have published state t
    {
      const unsigned int tgt = (unsigned int)t;
      for (;;) {
        unsigned int v = __hip_atomic_load(&f[lane], __ATOMIC_RELAXED, __HIP_MEMORY_SCOPE_AGENT);
        if (__all((int)(v >= tgt))) break;
        __builtin_amdgcn_s_sleep(1);
      }
    }
    __threadfence();  // acquire: invalidate caches so state loads see remote writes

    // ---- y = state @ Wh^T  (this wave: K slice [wave*512, wave*512+512))
    const half_t* ab = stc + (size_t)wave * 16 * 512 + lane * 8;
    half8 areg[16];
#pragma unroll
    for (int c = 0; c < 16; ++c) areg[c] = *(const half8*)(ab + c * 512);

    f32x4 a00 = {0.f,0.f,0.f,0.f}, a01 = {0.f,0.f,0.f,0.f};
    f32x4 a10 = {0.f,0.f,0.f,0.f}, a11 = {0.f,0.f,0.f,0.f};
#pragma unroll
    for (int c = 0; c < 16; c += 2) {
      a00 = MFMA16(areg[c],     breg[0][c],     a00);
      a10 = MFMA16(areg[c],     breg[1][c],     a10);
      a01 = MFMA16(areg[c + 1], breg[0][c + 1], a01);
      a11 = MFMA16(areg[c + 1], breg[1][c + 1], a11);
    }
    f32x4 y0 = a00 + a01;
    f32x4 y1 = a10 + a11;
#pragma unroll
    for (int r = 0; r < 4; ++r) {
      red_y[wave][0][kg * 4 + r][lm] = y0[r];
      red_y[wave][1][kg * 4 + r][lm] = y1[r];
    }
    __syncthreads();

    // ---- reduce K-partials, update state, publish
    const float yy0 = red_y[0][0][em][en] + red_y[1][0][em][en] + red_y[2][0][em][en] + red_y[3][0][em][en];
    const float yy1 = red_y[0][1][em][en] + red_y[1][1][em][en] + red_y[2][1][em][en] + red_y[3][1][em][en];
    const float sn0 = ca0 + yy0;
    const float sn1 = ca1 + yy1;
    stn[st_o0] = (half_t)sn0;
    stn[st_o1] = (half_t)sn1;
    s0 = sn0; s1 = sn1;
    __syncthreads();  // all stores drained (implied vmcnt(0)) before arrive
    if (tid == 0) {
      __threadfence();  // release: write back L2 so remote XCDs see state
      __hip_atomic_store(&f[local], (unsigned int)(t + 1), __ATOMIC_RELAXED, __HIP_MEMORY_SCOPE_AGENT);
    }
  }
}

__global__ __launch_bounds__(256, 1) void psrnn_readout_kernel(
    const float* __restrict__ Wr_w,   // [64][2048]
    const float* __restrict__ Wr_b,   // [64]
    const half_t* __restrict__ St,    // parity 0 = final state, frag layout
    float* __restrict__ out)          // [64][64]
{
  const int tid  = threadIdx.x;
  const int wave = tid >> 6;   // wave = replica = batch group
  const int lane = tid & 63;
  const int lm   = lane & 15;
  const int kg   = lane >> 4;
  const half_t* sb = St + (size_t)wave * 32768;

  f32x4 acc0 = {0.f,0.f,0.f,0.f}, acc1 = {0.f,0.f,0.f,0.f};
  f32x4 acc2 = {0.f,0.f,0.f,0.f}, acc3 = {0.f,0.f,0.f,0.f};
  for (int c = 0; c < 64; ++c) {
    half8 a = *(const half8*)(sb + (size_t)c * 512 + lane * 8);
    const float* p0 = Wr_w + (size_t)(lm) * NHID + c * 32 + kg * 8;
    half8 b0 = cvt8(*(const float4*)p0, *(const float4*)(p0 + 4));
    const float* p1 = p0 + (size_t)16 * NHID;
    half8 b1 = cvt8(*(const float4*)p1, *(const float4*)(p1 + 4));
    const float* p2 = p0 + (size_t)32 * NHID;
    half8 b2 = cvt8(*(const float4*)p2, *(const float4*)(p2 + 4));
    const float* p3 = p0 + (size_t)48 * NHID;
    half8 b3 = cvt8(*(const float4*)p3, *(const float4*)(p3 + 4));
    acc0 = MFMA16(a, b0, acc0);
    acc1 = MFMA16(a, b1, acc1);
    acc2 = MFMA16(a, b2, acc2);
    acc3 = MFMA16(a, b3, acc3);
  }
#pragma unroll
  for (int r = 0; r < 4; ++r) {
    const int b = wave * 16 + kg * 4 + r;
    out[b * NOUT +      lm] = acc0[r] + Wr_b[     lm];
    out[b * NOUT + 16 + lm] = acc1[r] + Wr_b[16 + lm];
    out[b * NOUT + 32 + lm] = acc2[r] + Wr_b[32 + lm];
    out[b * NOUT + 48 + lm] = acc3[r] + Wr_b[48 + lm];
  }
}

extern "C" void kernel_launch(void* const* d_in, const int* in_sizes, int n_in,
                              void* d_out, int out_size, void* d_ws, size_t ws_size,
                              hipStream_t stream) {
  const float* x    = (const float*)d_in[0];
  const float* Wi_w = (const float*)d_in[1];
  const float* Wi_b = (const float*)d_in[2];
  const float* Wh_w = (const float*)d_in[3];
  const float* Av   = (const float*)d_in[4];
  const float* Om   = (const float*)d_in[5];
  const float* Wr_w = (const float*)d_in[6];
  const float* Wr_b = (const float*)d_in[7];

  unsigned int* flags = (unsigned int*)d_ws;
  half_t* St = (half_t*)((char*)d_ws + 4096);

  psrnn_init_kernel<<<64, 256, 0, stream>>>(flags, St);
  psrnn_main_kernel<<<256, 256, 0, stream>>>(x, Wi_w, Wi_b, Wh_w, Av, Om, flags, St);
  psrnn_readout_kernel<<<1, 256, 0, stream>>>(Wr_w, Wr_b, St, (float*)d_out);
}

// Round 2
// 1790.342 us; speedup vs baseline: 7.0854x; 7.0854x over previous
//
#include <hip/hip_runtime.h>

// psRNN round 2: XCD-local replicas, fence-free L2 communication.
// 8 replicas (one per XCD) x 32 blocks. Replica r owns batches [8r, 8r+8)
// (MFMA M=16 rows: rows 8-15 duplicate rows 0-7). Block owns 64 neurons.
// Wh slice (64x2048) in VGPRs as f16 B-frags (256 VGPR/lane). Split-K over
// 4 waves (512 each) + LDS reduce. State double-buffered in ws, dedup'd
// frag layout half St[2][8][64 cg][4 kg][8 m][8 j] (32KB/replica/parity).
// State traffic uses sc0 (L1-bypass, XCD-L2-coherent) loads/stores via asm;
// no threadfence/wbl2/inv anywhere. Per-step flags are agent-scope (LLC).

typedef _Float16 half_t;
typedef _Float16 half8 __attribute__((ext_vector_type(8)));
typedef float f32x4 __attribute__((ext_vector_type(4)));

#define T_STEPS 512
#define NINP 64
#define NHID 2048
#define NOUT 64

#define MFMA16(A, B, C) __builtin_amdgcn_mfma_f32_16x16x32_f16(A, B, C, 0, 0, 0)

// ws layout:
//   [0, 1024)    : flags  uint[8][32]   (one 128B line per replica)
//   [1024, 1056) : roster uint[8]
//   [4096, 4096+512KB) : St half[2][8][64][4][8][8]

__device__ __forceinline__ half8 cvt8(float4 lo, float4 hi) {
  half8 h;
  h[0] = (half_t)lo.x; h[1] = (half_t)lo.y; h[2] = (half_t)lo.z; h[3] = (half_t)lo.w;
  h[4] = (half_t)hi.x; h[5] = (half_t)hi.y; h[6] = (half_t)hi.z; h[7] = (half_t)hi.w;
  return h;
}

__global__ void psrnn_init_kernel(unsigned* flags, unsigned* roster, uint4* st) {
  int g = blockIdx.x * blockDim.x + threadIdx.x;  // 16384
  uint4 v; v.x = 0x3C003C00u; v.y = 0x3C003C00u; v.z = 0x3C003C00u; v.w = 0x3C003C00u;
  st[g] = v;                                      // parity-0 state := fp16 1.0 (256KB)
  if (g < 256) flags[g] = 0;
  else if (g < 264) roster[g - 256] = 0;
}

__global__ __launch_bounds__(256, 1) void psrnn_main_kernel(
    const float* __restrict__ x,      // [512][64][64]
    const float* __restrict__ Wi_w,   // [2048][64]
    const float* __restrict__ Wi_b,   // [2048]
    const float* __restrict__ Wh_w,   // [2048][2048]
    const float* __restrict__ Av,     // [2048]
    const float* __restrict__ Om,     // [2048]
    unsigned* __restrict__ flags,
    unsigned* __restrict__ roster,
    half_t* __restrict__ St)
{
  __shared__ float red_y[4][4][16][17];  // [wave][tile][m][n]
  __shared__ float red_u[4][16][17];     // [tile][m][n]
  __shared__ unsigned slot_sh;

  const int tid  = threadIdx.x;
  const int wave = tid >> 6;
  const int lane = tid & 63;
  const int lm   = lane & 15;
  const int kg   = lane >> 4;

  unsigned xcd;
  asm volatile("s_getreg_b32 %0, hwreg(HW_REG_XCC_ID)" : "=s"(xcd));
  const int rep = (int)(xcd & 7u);
  if (tid == 0) slot_sh = atomicAdd(&roster[rep], 1u) & 31u;
  __syncthreads();
  const int slot = (int)slot_sh;
  const int n0   = slot * 64;   // this block's 64 neurons
  const int b0   = rep * 8;     // this replica's 8 batches

  // --- Wh slice -> VGPR B-frags: breg[nt][c] = neurons n0+16nt+lm, K chunk 16*wave+c
  half8 breg[4][16];
#pragma unroll
  for (int nt = 0; nt < 4; ++nt) {
#pragma unroll
    for (int c = 0; c < 16; ++c) {
      const float* p = Wh_w + (size_t)(n0 + nt * 16 + lm) * NHID + (wave * 512 + c * 32 + kg * 8);
      breg[nt][c] = cvt8(*(const float4*)p, *(const float4*)(p + 4));
    }
  }
  // --- Wi slice for this wave's u-tile (tile == wave)
  half8 wiReg[2];
#pragma unroll
  for (int c2 = 0; c2 < 2; ++c2) {
    const float* p = Wi_w + (size_t)(n0 + wave * 16 + lm) * NINP + (c2 * 32 + kg * 8);
    wiReg[c2] = cvt8(*(const float4*)p, *(const float4*)(p + 4));
  }

  // --- combiner constants: thread owns (m = tid>>4, n = en + 16*nt)
  const int m  = tid >> 4;
  const int en = tid & 15;
  float cAv[4], cOmv[4], cBv[4];
  int offh[4];
#pragma unroll
  for (int nt = 0; nt < 4; ++nt) {
    const int ng = n0 + nt * 16 + en;
    cAv[nt] = Av[ng]; cOmv[nt] = Om[ng]; cBv[nt] = Wi_b[ng];
    offh[nt] = (ng >> 5) * 256 + ((ng >> 3) & 3) * 64 + m * 8 + (ng & 7);
  }
  float s[4] = {1.f, 1.f, 1.f, 1.f};  // fp32 master state (rows >=8 mirror rows-8)

  unsigned* fl = flags + rep * 32;

  // x prefetch for t=0: A-frag rows = batch b0 + (lm&7)
  float4 xr0, xr1, xr2, xr3;
  {
    const float* xp = x + (size_t)(b0 + (lm & 7)) * NINP;
    xr0 = *(const float4*)(xp + kg * 8);
    xr1 = *(const float4*)(xp + kg * 8 + 4);
    xr2 = *(const float4*)(xp + 32 + kg * 8);
    xr3 = *(const float4*)(xp + 32 + kg * 8 + 4);
  }

  for (int t = 0; t < T_STEPS; ++t) {
    const int par = t & 1;
    const half_t* stc = St + (size_t)par * 131072 + rep * 16384;       // half units
    half_t* stn       = St + (size_t)(par ^ 1) * 131072 + rep * 16384;

    // ---- phase 1 (pre-wait, state-independent): u-tile via MFMA
    {
      half8 xa0 = cvt8(xr0, xr1);
      half8 xa1 = cvt8(xr2, xr3);
      f32x4 au = {0.f, 0.f, 0.f, 0.f};
      au = MFMA16(xa0, wiReg[0], au);
      au = MFMA16(xa1, wiReg[1], au);
#pragma unroll
      for (int r = 0; r < 4; ++r) red_u[wave][kg * 4 + r][lm] = au[r];
      if (t + 1 < T_STEPS) {
        const float* xp = x + ((size_t)(t + 1) * 64 + b0 + (lm & 7)) * NINP;
        xr0 = *(const float4*)(xp + kg * 8);
        xr1 = *(const float4*)(xp + kg * 8 + 4);
        xr2 = *(const float4*)(xp + 32 + kg * 8);
        xr3 = *(const float4*)(xp + 32 + kg * 8 + 4);
      }
    }

    // ---- phase 2: wait for all 32 replica blocks to have published state t
    {
      const unsigned tgt = (unsigned)t;
      const unsigned* fp = fl + (lane & 31);
      for (;;) {
        unsigned v = __hip_atomic_load(fp, __ATOMIC_RELAXED, __HIP_MEMORY_SCOPE_AGENT);
        if (__all((int)(v >= tgt))) break;
      }
    }

    // ---- phase 3: sc0 state loads (XCD L2) + MFMA over this wave's K slice
    const half_t* p0 = stc + wave * 4096 + kg * 64 + (lm & 7) * 8;
    const half_t* p1 = p0 + 2048;
    float4 Ar[16];
    asm volatile(
        "global_load_dwordx4 %0, %16, off sc0\n\t"
        "global_load_dwordx4 %1, %16, off offset:512 sc0\n\t"
        "global_load_dwordx4 %2, %16, off offset:1024 sc0\n\t"
        "global_load_dwordx4 %3, %16, off offset:1536 sc0\n\t"
        "global_load_dwordx4 %4, %16, off offset:2048 sc0\n\t"
        "global_load_dwordx4 %5, %16, off offset:2560 sc0\n\t"
        "global_load_dwordx4 %6, %16, off offset:3072 sc0\n\t"
        "global_load_dwordx4 %7, %16, off offset:3584 sc0\n\t"
        "global_load_dwordx4 %8, %17, off sc0\n\t"
        "global_load_dwordx4 %9, %17, off offset:512 sc0\n\t"
        "global_load_dwordx4 %10, %17, off offset:1024 sc0\n\t"
        "global_load_dwordx4 %11, %17, off offset:1536 sc0\n\t"
        "global_load_dwordx4 %12, %17, off offset:2048 sc0\n\t"
        "global_load_dwordx4 %13, %17, off offset:2560 sc0\n\t"
        "global_load_dwordx4 %14, %17, off offset:3072 sc0\n\t"
        "global_load_dwordx4 %15, %17, off offset:3584 sc0\n\t"
        "s_waitcnt vmcnt(0)"
        : "=&v"(Ar[0]), "=&v"(Ar[1]), "=&v"(Ar[2]), "=&v"(Ar[3]),
          "=&v"(Ar[4]), "=&v"(Ar[5]), "=&v"(Ar[6]), "=&v"(Ar[7]),
          "=&v"(Ar[8]), "=&v"(Ar[9]), "=&v"(Ar[10]), "=&v"(Ar[11]),
          "=&v"(Ar[12]), "=&v"(Ar[13]), "=&v"(Ar[14]), "=&v"(Ar[15])
        : "v"(p0), "v"(p1)
        : "memory");

    f32x4 a0 = {0.f,0.f,0.f,0.f}, a1 = {0.f,0.f,0.f,0.f};
    f32x4 a2 = {0.f,0.f,0.f,0.f}, a3 = {0.f,0.f,0.f,0.f};
#pragma unroll
    for (int c = 0; c < 16; ++c) {
      half8 a = __builtin_bit_cast(half8, Ar[c]);
      a0 = MFMA16(a, breg[0][c], a0);
      a1 = MFMA16(a, breg[1][c], a1);
      a2 = MFMA16(a, breg[2][c], a2);
      a3 = MFMA16(a, breg[3][c], a3);
    }
#pragma unroll
    for (int r = 0; r < 4; ++r) {
      red_y[wave][0][kg * 4 + r][lm] = a0[r];
      red_y[wave][1][kg * 4 + r][lm] = a1[r];
      red_y[wave][2][kg * 4 + r][lm] = a2[r];
      red_y[wave][3][kg * 4 + r][lm] = a3[r];
    }
    __syncthreads();

    // ---- phase 4: combine, cos path, publish state (sc0 stores -> XCD L2)
#pragma unroll
    for (int nt = 0; nt < 4; ++nt) {
      const float yv = red_y[0][nt][m][en] + red_y[1][nt][m][en] +
                       red_y[2][nt][m][en] + red_y[3][nt][m][en];
      const float uv = red_u[nt][m][en] + cBv[nt];
      const float sn = cAv[nt] * __cosf(cOmv[nt] * s[nt] + uv) + yv;
      s[nt] = sn;
      if (m < 8) {
        unsigned hv = (unsigned)__builtin_bit_cast(unsigned short, (half_t)sn);
        const half_t* sp = stn + offh[nt];
        asm volatile("global_store_short %0, %1, off sc0" :: "v"(sp), "v"(hv) : "memory");
      }
    }
    asm volatile("s_waitcnt vmcnt(0)" ::: "memory");  // stores committed to L2
    __syncthreads();
    if (tid == 0)
      __hip_atomic_store(&fl[slot], (unsigned)(t + 1), __ATOMIC_RELAXED, __HIP_MEMORY_SCOPE_AGENT);
  }
}

__global__ __launch_bounds__(256) void psrnn_readout_kernel(
    const float* __restrict__ Wr_w,   // [64][2048]
    const float* __restrict__ Wr_b,   // [64]
    const half_t* __restrict__ St,    // parity 0 = final state
    float* __restrict__ out)          // [64][64]
{
  const int tid  = threadIdx.x;
  const int wave = tid >> 6;          // handles replicas 2w, 2w+1
  const int lane = tid & 63;
  const int lm   = lane & 15;
  const int kg   = lane >> 4;

  f32x4 acc[2][4];
#pragma unroll
  for (int rr = 0; rr < 2; ++rr)
#pragma unroll
    for (int nt = 0; nt < 4; ++nt) acc[rr][nt] = (f32x4){0.f, 0.f, 0.f, 0.f};

  for (int cg = 0; cg < 64; ++cg) {
    half8 b[4];
#pragma unroll
    for (int nt = 0; nt < 4; ++nt) {
      const float* p = Wr_w + (size_t)(nt * 16 + lm) * NHID + cg * 32 + kg * 8;
      b[nt] = cvt8(*(const float4*)p, *(const float4*)(p + 4));
    }
#pragma unroll
    for (int rr = 0; rr < 2; ++rr) {
      const int rep = wave * 2 + rr;
      const half_t* ap = St + (size_t)rep * 16384 + cg * 256 + kg * 64 + (lm & 7) * 8;
      half8 a = *(const half8*)ap;
#pragma unroll
      for (int nt = 0; nt < 4; ++nt) acc[rr][nt] = MFMA16(a, b[nt], acc[rr][nt]);
    }
  }
  if (kg < 2) {
#pragma unroll
    for (int rr = 0; rr < 2; ++rr) {
      const int rep = wave * 2 + rr;
#pragma unroll
      for (int nt = 0; nt < 4; ++nt) {
#pragma unroll
        for (int r = 0; r < 4; ++r) {
          const int bidx = rep * 8 + kg * 4 + r;
          out[bidx * NOUT + nt * 16 + lm] = acc[rr][nt][r] + Wr_b[nt * 16 + lm];
        }
      }
    }
  }
}

extern "C" void kernel_launch(void* const* d_in, const int* in_sizes, int n_in,
                              void* d_out, int out_size, void* d_ws, size_t ws_size,
                              hipStream_t stream) {
  const float* x    = (const float*)d_in[0];
  const float* Wi_w = (const float*)d_in[1];
  const float* Wi_b = (const float*)d_in[2];
  const float* Wh_w = (const float*)d_in[3];
  const float* Av   = (const float*)d_in[4];
  const float* Om   = (const float*)d_in[5];
  const float* Wr_w = (const float*)d_in[6];
  const float* Wr_b = (const float*)d_in[7];

  unsigned* flags  = (unsigned*)d_ws;
  unsigned* roster = (unsigned*)((char*)d_ws + 1024);
  half_t*   St     = (half_t*)((char*)d_ws + 4096);

  psrnn_init_kernel<<<64, 256, 0, stream>>>(flags, roster, (uint4*)St);
  psrnn_main_kernel<<<256, 256, 0, stream>>>(x, Wi_w, Wi_b, Wh_w, Av, Om, flags, roster, St);
  psrnn_readout_kernel<<<1, 256, 0, stream>>>(Wr_w, Wr_b, St, (float*)d_out);
}